// Round 1
// baseline (1047.251 us; speedup 1.0000x reference)
//
#include <hip/hip_runtime.h>

#define NB 16
#define NN 256
#define FF 64
#define NC 32
#define EPSF 1e-10f

__device__ __forceinline__ float sigmoid_(float v){ return 1.0f/(1.0f+__expf(-v)); }
__device__ __forceinline__ float silu_(float v){ return v/(1.0f+__expf(-v)); }
__device__ __forceinline__ float wsum64(float v){
  #pragma unroll
  for (int off=32; off>0; off>>=1) v += __shfl_xor(v, off, 64);
  return v;
}

// Kernel A: per-node projections through the first edge layer.
// hip_[b,n,t] = sum_k h[b,n,k]*ew1[k,t] + eb1[t]   (h_i contribution + bias)
// hjp_[b,n,t] = sum_k h[b,n,k]*ew1[64+k,t]         (h_j contribution)
__global__ __launch_bounds__(64) void sake_proj(
    const float* __restrict__ h, const float* __restrict__ ew1,
    const float* __restrict__ eb1, float* __restrict__ hip_, float* __restrict__ hjp_)
{
  const int bn = blockIdx.x;
  const int t = threadIdx.x;
  __shared__ float hs[FF];
  hs[t] = h[bn*FF + t];
  __syncthreads();
  float a1 = eb1[t];
  float a2 = 0.f;
  #pragma unroll 16
  for (int k=0;k<FF;++k){
    const float hv = hs[k];
    a1 += hv * ew1[k*FF + t];
    a2 += hv * ew1[(FF+k)*FF + t];
  }
  hip_[bn*FF + t] = a1;
  hjp_[bn*FF + t] = a2;
}

// Kernel B: one block per (b,i). 4 waves, each handles 64 j's in groups of 4.
__global__ __launch_bounds__(256, 2) void sake_main(
    const float* __restrict__ h, const float* __restrict__ x,
    const float* __restrict__ ew1, const float* __restrict__ ew2, const float* __restrict__ eb2,
    const float* __restrict__ aw, const float* __restrict__ ab,
    const float* __restrict__ cw1, const float* __restrict__ cb1,
    const float* __restrict__ cw2, const float* __restrict__ cb2,
    const float* __restrict__ pw1, const float* __restrict__ pb1,
    const float* __restrict__ pw2, const float* __restrict__ pb2,
    const float* __restrict__ nw1, const float* __restrict__ nb1,
    const float* __restrict__ nw2, const float* __restrict__ nb2,
    const float* __restrict__ xw1, const float* __restrict__ xb1,
    const float* __restrict__ xw2,
    const float* __restrict__ hip_, const float* __restrict__ hjp_,
    float* __restrict__ out_h, float* __restrict__ out_x)
{
  const int bi = blockIdx.x;
  const int b = bi >> 8;
  const int i = bi & 255;
  const int tid = threadIdx.x;
  const int wave = tid >> 6;
  const int lane = tid & 63;

  __shared__ float s_ew2[FF*FF];
  __shared__ float s_cw1[FF*FF];
  __shared__ float s_xw1[FF*FF];
  __shared__ float s_cw2[FF*NC];
  __shared__ float s_hipr[FF], s_ew1r[FF], s_eb2[FF], s_cb1[FF], s_xb1[FF], s_aw[FF], s_xw2[FF];
  __shared__ float s_cb2[NC];
  __shared__ float s_x[NN*3];
  __shared__ __align__(16) float s_a[4][FF*4];   // per-wave activation slice (a1, then silu(c1))
  __shared__ __align__(16) float s_he[4][FF*4];  // per-wave gated h_e
  __shared__ float s_rh[4][FF];
  __shared__ float s_rc[4][NC][3];
  __shared__ float s_rx[4][3];
  __shared__ float s_cn[NC];
  __shared__ float s_t1[FF];
  __shared__ float s_ni[3*FF];

  for (int idx = tid; idx < FF*FF; idx += 256){
    s_ew2[idx] = ew2[idx];
    s_cw1[idx] = cw1[idx];
    s_xw1[idx] = xw1[idx];
  }
  for (int idx = tid; idx < FF*NC; idx += 256) s_cw2[idx] = cw2[idx];
  for (int idx = tid; idx < NN*3; idx += 256) s_x[idx] = x[b*NN*3 + idx];
  if (tid < FF){
    s_hipr[tid] = hip_[(size_t)bi*FF + tid];
    s_ew1r[tid] = ew1[128*FF + tid];
    s_eb2[tid] = eb2[tid];
    s_cb1[tid] = cb1[tid];
    s_xb1[tid] = xb1[tid];
    s_aw[tid]  = aw[tid];
    s_xw2[tid] = xw2[tid];
  } else if (tid < FF + NC){
    s_cb2[tid-FF] = cb2[tid-FF];
  }
  __syncthreads();

  const float xi0 = s_x[i*3+0], xi1 = s_x[i*3+1], xi2 = s_x[i*3+2];
  const float abv = ab[0];
  const float awv = s_aw[lane];
  const float xw2v = s_xw2[lane];

  float hagg = 0.f;
  float comb0 = 0.f, comb1 = 0.f, comb2 = 0.f;
  float xacc0 = 0.f, xacc1 = 0.f, xacc2 = 0.f;

  const int cidx = lane & 31;
  const int khalf = (lane >> 5) * 32;

  for (int jt = 0; jt < 16; ++jt){
    const int jbase = wave*64 + jt*4;
    float dxa[4], dya[4], dza[4], inr[4];
    float a1[4];
    #pragma unroll
    for (int jj=0;jj<4;++jj){
      const int j = jbase + jj;
      const float d0 = xi0 - s_x[j*3+0];
      const float d1 = xi1 - s_x[j*3+1];
      const float d2 = xi2 - s_x[j*3+2];
      const float nr = sqrtf(d0*d0 + d1*d1 + d2*d2 + EPSF);
      dxa[jj]=d0; dya[jj]=d1; dza[jj]=d2;
      inr[jj] = 1.0f/(nr + EPSF);
      const float l1 = s_hipr[lane] + hjp_[((size_t)(b*NN + j))*FF + lane] + nr*s_ew1r[lane];
      a1[jj] = silu_(l1);
    }
    *(float4*)&s_a[wave][lane*4] = make_float4(a1[0],a1[1],a1[2],a1[3]);
    __syncthreads();

    // lin2 -> gated h_e
    float acc[4];
    {
      const float bias = s_eb2[lane];
      acc[0]=bias; acc[1]=bias; acc[2]=bias; acc[3]=bias;
      #pragma unroll 16
      for (int k=0;k<FF;++k){
        const float w = s_ew2[k*FF + lane];
        const float4 av = *(const float4*)&s_a[wave][k*4];
        acc[0] += av.x*w; acc[1] += av.y*w; acc[2] += av.z*w; acc[3] += av.w*w;
      }
    }
    float he[4];
    #pragma unroll
    for (int jj=0;jj<4;++jj){
      const float hp = silu_(acc[jj]);
      const float att = sigmoid_(wsum64(hp*awv) + abv);
      he[jj] = hp*att;
      hagg += he[jj];
    }
    *(float4*)&s_he[wave][lane*4] = make_float4(he[0],he[1],he[2],he[3]);
    __syncthreads();

    // c1 = silu(h_e @ cw1 + cb1)
    {
      const float bias = s_cb1[lane];
      acc[0]=bias; acc[1]=bias; acc[2]=bias; acc[3]=bias;
      #pragma unroll 16
      for (int k=0;k<FF;++k){
        const float w = s_cw1[k*FF + lane];
        const float4 av = *(const float4*)&s_he[wave][k*4];
        acc[0] += av.x*w; acc[1] += av.y*w; acc[2] += av.z*w; acc[3] += av.w*w;
      }
    }
    #pragma unroll
    for (int jj=0;jj<4;++jj) a1[jj] = silu_(acc[jj]);
    *(float4*)&s_a[wave][lane*4] = make_float4(a1[0],a1[1],a1[2],a1[3]);
    __syncthreads();

    // coeff = c1 @ cw2 + cb2 ; comb += unit * coeff
    {
      float pc[4] = {0.f,0.f,0.f,0.f};
      #pragma unroll 8
      for (int kk=0;kk<32;++kk){
        const int k = khalf + kk;
        const float w = s_cw2[k*NC + cidx];
        const float4 av = *(const float4*)&s_a[wave][k*4];
        pc[0] += av.x*w; pc[1] += av.y*w; pc[2] += av.z*w; pc[3] += av.w*w;
      }
      #pragma unroll
      for (int jj=0;jj<4;++jj) pc[jj] += __shfl_down(pc[jj], 32, 64);
      if (lane < 32){
        #pragma unroll
        for (int jj=0;jj<4;++jj){
          const float cf = pc[jj] + s_cb2[lane];
          comb0 += dxa[jj]*inr[jj]*cf;
          comb1 += dya[jj]*inr[jj]*cf;
          comb2 += dza[jj]*inr[jj]*cf;
        }
      }
    }

    // trans = silu(h_e @ xw1 + xb1) @ xw2 ; x-accumulate
    {
      const float bias = s_xb1[lane];
      acc[0]=bias; acc[1]=bias; acc[2]=bias; acc[3]=bias;
      #pragma unroll 16
      for (int k=0;k<FF;++k){
        const float w = s_xw1[k*FF + lane];
        const float4 av = *(const float4*)&s_he[wave][k*4];
        acc[0] += av.x*w; acc[1] += av.y*w; acc[2] += av.z*w; acc[3] += av.w*w;
      }
      #pragma unroll
      for (int jj=0;jj<4;++jj){
        const float tr = wsum64(silu_(acc[jj]) * xw2v);
        xacc0 += dxa[jj]*tr;
        xacc1 += dya[jj]*tr;
        xacc2 += dza[jj]*tr;
      }
    }
    __syncthreads();
  }

  // cross-wave reduction
  s_rh[wave][lane] = hagg;
  if (lane < 32){ s_rc[wave][lane][0]=comb0; s_rc[wave][lane][1]=comb1; s_rc[wave][lane][2]=comb2; }
  if (lane == 0){ s_rx[wave][0]=xacc0; s_rx[wave][1]=xacc1; s_rx[wave][2]=xacc2; }
  __syncthreads();

  // Phase 2: node-level MLPs on wave 0 (block-wide barriers keep all waves legal)
  float haggT = 0.f, hval = 0.f;
  if (wave == 0){
    haggT = s_rh[0][lane]+s_rh[1][lane]+s_rh[2][lane]+s_rh[3][lane];
    hval = h[(size_t)bi*FF + lane];
    if (lane < 32){
      const float c0 = s_rc[0][lane][0]+s_rc[1][lane][0]+s_rc[2][lane][0]+s_rc[3][lane][0];
      const float c1 = s_rc[0][lane][1]+s_rc[1][lane][1]+s_rc[2][lane][1]+s_rc[3][lane][1];
      const float c2 = s_rc[0][lane][2]+s_rc[1][lane][2]+s_rc[2][lane][2]+s_rc[3][lane][2];
      s_cn[lane] = c0*c0 + c1*c1 + c2*c2;
    }
  }
  __syncthreads();
  if (wave == 0){
    float p1 = pb1[lane];
    #pragma unroll 8
    for (int c=0;c<NC;++c) p1 += s_cn[c]*pw1[c*FF + lane];
    s_t1[lane] = silu_(p1);
  }
  __syncthreads();
  if (wave == 0){
    float p2 = pb2[lane];
    #pragma unroll 8
    for (int k=0;k<FF;++k) p2 += s_t1[k]*pw2[k*FF + lane];
    s_ni[lane] = hval;
    s_ni[FF + lane] = haggT;
    s_ni[2*FF + lane] = p2;
  }
  __syncthreads();
  if (wave == 0){
    float n1 = nb1[lane];
    #pragma unroll 8
    for (int k=0;k<3*FF;++k) n1 += s_ni[k]*nw1[k*FF + lane];
    s_t1[lane] = silu_(n1);
  }
  __syncthreads();
  if (wave == 0){
    float n2 = nb2[lane];
    #pragma unroll 8
    for (int k=0;k<FF;++k) n2 += s_t1[k]*nw2[k*FF + lane];
    out_h[(size_t)bi*FF + lane] = hval + n2;
    if (lane < 3){
      const float xs = s_rx[0][lane]+s_rx[1][lane]+s_rx[2][lane]+s_rx[3][lane];
      out_x[(size_t)bi*3 + lane] = s_x[i*3 + lane] + xs*(1.0f/256.0f);
    }
  }
}

extern "C" void kernel_launch(void* const* d_in, const int* in_sizes, int n_in,
                              void* d_out, int out_size, void* d_ws, size_t ws_size,
                              hipStream_t stream) {
  const float* h   = (const float*)d_in[0];
  const float* x   = (const float*)d_in[1];
  const float* ew1 = (const float*)d_in[2];
  const float* eb1 = (const float*)d_in[3];
  const float* ew2 = (const float*)d_in[4];
  const float* eb2 = (const float*)d_in[5];
  const float* aw  = (const float*)d_in[6];
  const float* ab  = (const float*)d_in[7];
  const float* cw1 = (const float*)d_in[8];
  const float* cb1 = (const float*)d_in[9];
  const float* cw2 = (const float*)d_in[10];
  const float* cb2 = (const float*)d_in[11];
  const float* pw1 = (const float*)d_in[12];
  const float* pb1 = (const float*)d_in[13];
  const float* pw2 = (const float*)d_in[14];
  const float* pb2 = (const float*)d_in[15];
  const float* nw1 = (const float*)d_in[16];
  const float* nb1 = (const float*)d_in[17];
  const float* nw2 = (const float*)d_in[18];
  const float* nb2 = (const float*)d_in[19];
  const float* xw1 = (const float*)d_in[20];
  const float* xb1 = (const float*)d_in[21];
  const float* xw2 = (const float*)d_in[22];

  float* hip_ = (float*)d_ws;
  float* hjp_ = hip_ + (size_t)NB*NN*FF;
  float* out_h = (float*)d_out;
  float* out_x = out_h + (size_t)NB*NN*FF;

  sake_proj<<<NB*NN, 64, 0, stream>>>(h, ew1, eb1, hip_, hjp_);
  sake_main<<<NB*NN, 256, 0, stream>>>(h, x, ew1, ew2, eb2, aw, ab, cw1, cb1, cw2, cb2,
                                       pw1, pb1, pw2, pb2, nw1, nb1, nw2, nb2,
                                       xw1, xb1, xw2, hip_, hjp_, out_h, out_x);
}

// Round 2
// 857.289 us; speedup vs baseline: 1.2216x; 1.2216x over previous
//
#include <hip/hip_runtime.h>

#define NB 16
#define NN 256
#define FF 64
#define NC 32
#define EPSF 1e-10f
#define WAVES 8

__device__ __forceinline__ float rcp_(float v){ return __builtin_amdgcn_rcpf(v); }
__device__ __forceinline__ float sigmoid_(float v){ return rcp_(1.0f+__expf(-v)); }
__device__ __forceinline__ float silu_(float v){ return v*rcp_(1.0f+__expf(-v)); }
__device__ __forceinline__ float wsum64(float v){
  #pragma unroll
  for (int off=32; off>0; off>>=1) v += __shfl_xor(v, off, 64);
  return v;
}

// Kernel A: per-node projections through the first edge layer.
__global__ __launch_bounds__(64) void sake_proj(
    const float* __restrict__ h, const float* __restrict__ ew1,
    const float* __restrict__ eb1, float* __restrict__ hip_, float* __restrict__ hjp_)
{
  const int bn = blockIdx.x;
  const int t = threadIdx.x;
  __shared__ float hs[FF];
  hs[t] = h[bn*FF + t];
  __syncthreads();
  float a1 = eb1[t];
  float a2 = 0.f;
  #pragma unroll 16
  for (int k=0;k<FF;++k){
    const float hv = hs[k];
    a1 += hv * ew1[k*FF + t];
    a2 += hv * ew1[(FF+k)*FF + t];
  }
  hip_[bn*FF + t] = a1;
  hjp_[bn*FF + t] = a2;
}

// Kernel B: one block per (b,i). 8 waves x 32 j each, 4 j at a time.
// No intra-loop barriers: each wave touches only its own s_a/s_he slice.
__global__ __launch_bounds__(512, 4) void sake_main(
    const float* __restrict__ h, const float* __restrict__ x,
    const float* __restrict__ ew1, const float* __restrict__ ew2, const float* __restrict__ eb2,
    const float* __restrict__ aw, const float* __restrict__ ab,
    const float* __restrict__ cw1, const float* __restrict__ cb1,
    const float* __restrict__ cw2, const float* __restrict__ cb2,
    const float* __restrict__ pw1, const float* __restrict__ pb1,
    const float* __restrict__ pw2, const float* __restrict__ pb2,
    const float* __restrict__ nw1, const float* __restrict__ nb1,
    const float* __restrict__ nw2, const float* __restrict__ nb2,
    const float* __restrict__ xw1, const float* __restrict__ xb1,
    const float* __restrict__ xw2,
    const float* __restrict__ hip_, const float* __restrict__ hjp_,
    float* __restrict__ out_h, float* __restrict__ out_x)
{
  const int bi = blockIdx.x;
  const int b = bi >> 8;
  const int i = bi & 255;
  const int tid = threadIdx.x;
  const int wave = tid >> 6;
  const int lane = tid & 63;

  __shared__ float s_ew2[FF*FF];
  __shared__ float s_cw1[FF*FF];
  __shared__ float s_xw1[FF*FF];
  __shared__ float s_cw2[FF*NC];
  __shared__ float s_hipr[FF], s_ew1r[FF], s_eb2[FF], s_cb1[FF], s_xb1[FF], s_aw[FF], s_xw2[FF];
  __shared__ float s_cb2[NC];
  __shared__ float s_x[NN*3];
  __shared__ __align__(16) float s_a[WAVES][FF*4];   // per-wave act slice; post-loop: reduction scratch
  __shared__ __align__(16) float s_he[WAVES][FF*4];  // per-wave gated h_e

  // post-loop scratch aliased into s_a (1592 of 2048 floats) — guarded by barriers
  float* s_rh = &s_a[0][0];          // [WAVES][FF]
  float* s_rc = s_rh + WAVES*FF;     // [WAVES][NC][3]
  float* s_rx = s_rc + WAVES*NC*3;   // [WAVES][3]
  float* s_cn = s_rx + WAVES*3;      // [NC]
  float* s_t1 = s_cn + NC;           // [FF]
  float* s_ni = s_t1 + FF;           // [3*FF]

  for (int idx = tid; idx < FF*FF; idx += 512){
    s_ew2[idx] = ew2[idx];
    s_cw1[idx] = cw1[idx];
    s_xw1[idx] = xw1[idx];
  }
  for (int idx = tid; idx < FF*NC; idx += 512) s_cw2[idx] = cw2[idx];
  for (int idx = tid; idx < NN*3; idx += 512) s_x[idx] = x[b*NN*3 + idx];
  if (tid < FF){
    s_hipr[tid] = hip_[(size_t)bi*FF + tid];
    s_ew1r[tid] = ew1[128*FF + tid];
    s_eb2[tid] = eb2[tid];
    s_cb1[tid] = cb1[tid];
    s_xb1[tid] = xb1[tid];
    s_aw[tid]  = aw[tid];
    s_xw2[tid] = xw2[tid];
  } else if (tid < FF + NC){
    s_cb2[tid-FF] = cb2[tid-FF];
  }
  __syncthreads();

  const float xi0 = s_x[i*3+0], xi1 = s_x[i*3+1], xi2 = s_x[i*3+2];
  const float abv = ab[0];
  const float awv = s_aw[lane];
  const float xw2v = s_xw2[lane];

  float hagg = 0.f;
  float comb0 = 0.f, comb1 = 0.f, comb2 = 0.f;
  float xacc0 = 0.f, xacc1 = 0.f, xacc2 = 0.f;

  const int cidx = lane & 31;
  const int khalf = (lane >> 5) * 32;

  for (int jt = 0; jt < 8; ++jt){
    const int jbase = wave*32 + jt*4;
    float dxa[4], dya[4], dza[4], inr[4];
    float a1[4];
    #pragma unroll
    for (int jj=0;jj<4;++jj){
      const int j = jbase + jj;
      const float d0 = xi0 - s_x[j*3+0];
      const float d1 = xi1 - s_x[j*3+1];
      const float d2 = xi2 - s_x[j*3+2];
      const float s = d0*d0 + d1*d1 + d2*d2 + EPSF;
      const float nr = __builtin_amdgcn_sqrtf(s);
      dxa[jj]=d0; dya[jj]=d1; dza[jj]=d2;
      inr[jj] = rcp_(nr + EPSF);
      const float l1 = s_hipr[lane] + hjp_[((size_t)(b*NN + j))*FF + lane] + nr*s_ew1r[lane];
      a1[jj] = silu_(l1);
    }
    *(float4*)&s_a[wave][lane*4] = make_float4(a1[0],a1[1],a1[2],a1[3]);

    // lin2 -> gated h_e
    float acc[4];
    {
      const float bias = s_eb2[lane];
      acc[0]=bias; acc[1]=bias; acc[2]=bias; acc[3]=bias;
      #pragma unroll 16
      for (int k=0;k<FF;++k){
        const float w = s_ew2[k*FF + lane];
        const float4 av = *(const float4*)&s_a[wave][k*4];
        acc[0] += av.x*w; acc[1] += av.y*w; acc[2] += av.z*w; acc[3] += av.w*w;
      }
    }
    float he[4];
    #pragma unroll
    for (int jj=0;jj<4;++jj){
      const float hp = silu_(acc[jj]);
      const float att = sigmoid_(wsum64(hp*awv) + abv);
      he[jj] = hp*att;
      hagg += he[jj];
    }
    *(float4*)&s_he[wave][lane*4] = make_float4(he[0],he[1],he[2],he[3]);

    // c1 = silu(h_e @ cw1 + cb1)
    {
      const float bias = s_cb1[lane];
      acc[0]=bias; acc[1]=bias; acc[2]=bias; acc[3]=bias;
      #pragma unroll 16
      for (int k=0;k<FF;++k){
        const float w = s_cw1[k*FF + lane];
        const float4 av = *(const float4*)&s_he[wave][k*4];
        acc[0] += av.x*w; acc[1] += av.y*w; acc[2] += av.z*w; acc[3] += av.w*w;
      }
    }
    #pragma unroll
    for (int jj=0;jj<4;++jj) a1[jj] = silu_(acc[jj]);
    *(float4*)&s_a[wave][lane*4] = make_float4(a1[0],a1[1],a1[2],a1[3]);

    // coeff = c1 @ cw2 + cb2 ; comb += unit * coeff
    {
      float pc[4] = {0.f,0.f,0.f,0.f};
      #pragma unroll 8
      for (int kk=0;kk<32;++kk){
        const int k = khalf + kk;
        const float w = s_cw2[k*NC + cidx];
        const float4 av = *(const float4*)&s_a[wave][k*4];
        pc[0] += av.x*w; pc[1] += av.y*w; pc[2] += av.z*w; pc[3] += av.w*w;
      }
      #pragma unroll
      for (int jj=0;jj<4;++jj) pc[jj] += __shfl_down(pc[jj], 32, 64);
      if (lane < 32){
        #pragma unroll
        for (int jj=0;jj<4;++jj){
          const float cf = pc[jj] + s_cb2[lane];
          comb0 += dxa[jj]*inr[jj]*cf;
          comb1 += dya[jj]*inr[jj]*cf;
          comb2 += dza[jj]*inr[jj]*cf;
        }
      }
    }

    // trans = silu(h_e @ xw1 + xb1) @ xw2 ; x-accumulate
    {
      const float bias = s_xb1[lane];
      acc[0]=bias; acc[1]=bias; acc[2]=bias; acc[3]=bias;
      #pragma unroll 16
      for (int k=0;k<FF;++k){
        const float w = s_xw1[k*FF + lane];
        const float4 av = *(const float4*)&s_he[wave][k*4];
        acc[0] += av.x*w; acc[1] += av.y*w; acc[2] += av.z*w; acc[3] += av.w*w;
      }
      #pragma unroll
      for (int jj=0;jj<4;++jj){
        const float tr = wsum64(silu_(acc[jj]) * xw2v);
        xacc0 += dxa[jj]*tr;
        xacc1 += dya[jj]*tr;
        xacc2 += dza[jj]*tr;
      }
    }
  }

  // all waves done with s_a/s_he before scratch aliasing
  __syncthreads();
  s_rh[wave*FF + lane] = hagg;
  if (lane < 32){
    s_rc[(wave*NC + lane)*3 + 0] = comb0;
    s_rc[(wave*NC + lane)*3 + 1] = comb1;
    s_rc[(wave*NC + lane)*3 + 2] = comb2;
  }
  if (lane == 0){
    s_rx[wave*3+0]=xacc0; s_rx[wave*3+1]=xacc1; s_rx[wave*3+2]=xacc2;
  }
  __syncthreads();

  // Phase 2: node-level MLPs on wave 0 (block-wide barriers keep all waves legal)
  float haggT = 0.f, hval = 0.f;
  if (wave == 0){
    #pragma unroll
    for (int w=0; w<WAVES; ++w) haggT += s_rh[w*FF + lane];
    hval = h[(size_t)bi*FF + lane];
    if (lane < 32){
      float c0=0.f, c1=0.f, c2=0.f;
      #pragma unroll
      for (int w=0; w<WAVES; ++w){
        c0 += s_rc[(w*NC + lane)*3 + 0];
        c1 += s_rc[(w*NC + lane)*3 + 1];
        c2 += s_rc[(w*NC + lane)*3 + 2];
      }
      s_cn[lane] = c0*c0 + c1*c1 + c2*c2;
    }
  }
  __syncthreads();
  if (wave == 0){
    float p1 = pb1[lane];
    #pragma unroll 8
    for (int c=0;c<NC;++c) p1 += s_cn[c]*pw1[c*FF + lane];
    s_t1[lane] = silu_(p1);
  }
  __syncthreads();
  if (wave == 0){
    float p2 = pb2[lane];
    #pragma unroll 8
    for (int k=0;k<FF;++k) p2 += s_t1[k]*pw2[k*FF + lane];
    s_ni[lane] = hval;
    s_ni[FF + lane] = haggT;
    s_ni[2*FF + lane] = p2;
  }
  __syncthreads();
  if (wave == 0){
    float n1 = nb1[lane];
    #pragma unroll 8
    for (int k=0;k<3*FF;++k) n1 += s_ni[k]*nw1[k*FF + lane];
    s_t1[lane] = silu_(n1);
  }
  __syncthreads();
  if (wave == 0){
    float n2 = nb2[lane];
    #pragma unroll 8
    for (int k=0;k<FF;++k) n2 += s_t1[k]*nw2[k*FF + lane];
    out_h[(size_t)bi*FF + lane] = hval + n2;
    if (lane < 3){
      float xs = 0.f;
      #pragma unroll
      for (int w=0; w<WAVES; ++w) xs += s_rx[w*3 + lane];
      out_x[(size_t)bi*3 + lane] = s_x[i*3 + lane] + xs*(1.0f/256.0f);
    }
  }
}

extern "C" void kernel_launch(void* const* d_in, const int* in_sizes, int n_in,
                              void* d_out, int out_size, void* d_ws, size_t ws_size,
                              hipStream_t stream) {
  const float* h   = (const float*)d_in[0];
  const float* x   = (const float*)d_in[1];
  const float* ew1 = (const float*)d_in[2];
  const float* eb1 = (const float*)d_in[3];
  const float* ew2 = (const float*)d_in[4];
  const float* eb2 = (const float*)d_in[5];
  const float* aw  = (const float*)d_in[6];
  const float* ab  = (const float*)d_in[7];
  const float* cw1 = (const float*)d_in[8];
  const float* cb1 = (const float*)d_in[9];
  const float* cw2 = (const float*)d_in[10];
  const float* cb2 = (const float*)d_in[11];
  const float* pw1 = (const float*)d_in[12];
  const float* pb1 = (const float*)d_in[13];
  const float* pw2 = (const float*)d_in[14];
  const float* pb2 = (const float*)d_in[15];
  const float* nw1 = (const float*)d_in[16];
  const float* nb1 = (const float*)d_in[17];
  const float* nw2 = (const float*)d_in[18];
  const float* nb2 = (const float*)d_in[19];
  const float* xw1 = (const float*)d_in[20];
  const float* xb1 = (const float*)d_in[21];
  const float* xw2 = (const float*)d_in[22];

  float* hip_ = (float*)d_ws;
  float* hjp_ = hip_ + (size_t)NB*NN*FF;
  float* out_h = (float*)d_out;
  float* out_x = out_h + (size_t)NB*NN*FF;

  sake_proj<<<NB*NN, 64, 0, stream>>>(h, ew1, eb1, hip_, hjp_);
  sake_main<<<NB*NN, 512, 0, stream>>>(h, x, ew1, ew2, eb2, aw, ab, cw1, cb1, cw2, cb2,
                                       pw1, pb1, pw2, pb2, nw1, nb1, nw2, nb2,
                                       xw1, xb1, xw2, hip_, hjp_, out_h, out_x);
}

// Round 3
// 176.684 us; speedup vs baseline: 5.9273x; 4.8521x over previous
//
#include <hip/hip_runtime.h>
#include <hip/hip_bf16.h>

#define NB 16
#define NN 256
#define FF 64
#define NC 32
#define EPSF 1e-10f

typedef __attribute__((ext_vector_type(8))) short s16x8;
typedef __attribute__((ext_vector_type(4))) float f32x4;

__device__ __forceinline__ float rcp_(float v){ return __builtin_amdgcn_rcpf(v); }
__device__ __forceinline__ float sigmoid_(float v){ return rcp_(1.0f+__expf(-v)); }
__device__ __forceinline__ float silu_(float v){ return v*rcp_(1.0f+__expf(-v)); }
__device__ __forceinline__ short f2bf(float f){
  __hip_bfloat16 h = __float2bfloat16(f);
  return __builtin_bit_cast(short, h);
}

// Kernel A: per-node projections through the first edge layer (fp32).
__global__ __launch_bounds__(64) void sake_proj(
    const float* __restrict__ h, const float* __restrict__ ew1,
    const float* __restrict__ eb1, float* __restrict__ hip_, float* __restrict__ hjp_)
{
  const int bn = blockIdx.x;
  const int t = threadIdx.x;
  __shared__ float hs[FF];
  hs[t] = h[bn*FF + t];
  __syncthreads();
  float a1 = eb1[t];
  float a2 = 0.f;
  #pragma unroll 16
  for (int k=0;k<FF;++k){
    const float hv = hs[k];
    a1 += hv * ew1[k*FF + t];
    a2 += hv * ew1[(FF+k)*FF + t];
  }
  hip_[bn*FF + t] = a1;
  hjp_[bn*FF + t] = a2;
}

// Kernel B: one block per (b,i); 8 waves x 32 j; bf16 MFMA for all edge GEMMs.
// Swapped-operand scheme: D = W^T (A-frag) x act^T (B-frag); act B-frags built
// directly (a1) or via XOR-swizzled per-wave LDS bounce (h_e, c1).
__global__ __launch_bounds__(512, 4) void sake_main(
    const float* __restrict__ h, const float* __restrict__ x,
    const float* __restrict__ ew1, const float* __restrict__ ew2, const float* __restrict__ eb2,
    const float* __restrict__ aw, const float* __restrict__ ab,
    const float* __restrict__ cw1, const float* __restrict__ cb1,
    const float* __restrict__ cw2, const float* __restrict__ cb2,
    const float* __restrict__ pw1, const float* __restrict__ pb1,
    const float* __restrict__ pw2, const float* __restrict__ pb2,
    const float* __restrict__ nw1, const float* __restrict__ nb1,
    const float* __restrict__ nw2, const float* __restrict__ nb2,
    const float* __restrict__ xw1, const float* __restrict__ xb1,
    const float* __restrict__ xw2,
    const float* __restrict__ hip_, const float* __restrict__ hjp_,
    float* __restrict__ out_h, float* __restrict__ out_x)
{
  const int bi = blockIdx.x;
  const int b = bi >> 8;
  const int tid = threadIdx.x;
  const int wave = tid >> 6;
  const int l = tid & 63;
  const int g = l >> 4;
  const int r15 = l & 15;

  // weights as swapped A-frags (bf16): W^T[out][in], slot(l,e)=W[in=kt*32+g*8+e][out=mt*16+r15]
  __shared__ short s_wE[8*64*8];   // ew2^T  8KB
  __shared__ short s_wC[8*64*8];   // cw1^T  8KB
  __shared__ short s_wX[8*64*8];   // xw1^T  8KB
  __shared__ short s_w2[4*64*8];   // cw2^T  4KB
  __shared__ short s_sT[8][2048];  // per-wave act^T scratch [32j][64n] bf16, XOR-swizzled (32KB)
  __shared__ float s_dx[8][32], s_dy[8][32], s_dz[8][32], s_nr[8][32];
  __shared__ float s_ux[8][32], s_uy[8][32], s_uz[8][32];
  __shared__ float s_hip[FF], s_e1r[FF], s_eb2[FF], s_cb1[FF], s_xb1[FF], s_xw2v[FF], s_awv[FF];
  __shared__ float s_cb2[NC];
  __shared__ float s_rh[8*FF];
  __shared__ float s_rc[8*NC*3];
  __shared__ float s_rx[8*3];
  __shared__ float s_cn[NC], s_t1[FF], s_ni[3*FF];

  // ---- prologue: pack weights to bf16 fragments ----
  {
    const int f  = tid >> 6;           // frag id 0..7
    const int sl = tid & 63;
    const int sg = sl >> 4, sr = sl & 15;
    const int mt = f >> 1, kt = f & 1;
    const int ob = mt*16 + sr;
    const int ib = kt*32 + sg*8;
    const int dbase = (f*64 + sl)*8;
    #pragma unroll
    for (int e=0;e<8;++e){
      s_wE[dbase+e] = f2bf(ew2[(ib+e)*FF + ob]);
      s_wC[dbase+e] = f2bf(cw1[(ib+e)*FF + ob]);
      s_wX[dbase+e] = f2bf(xw1[(ib+e)*FF + ob]);
    }
    if (f < 4){
      #pragma unroll
      for (int e=0;e<8;++e)
        s_w2[dbase+e] = f2bf(cw2[(ib+e)*NC + ob]);
    }
  }
  if (tid < FF){
    s_hip[tid]  = hip_[(size_t)bi*FF + tid];
    s_e1r[tid]  = ew1[128*FF + tid];
    s_eb2[tid]  = eb2[tid];
    s_cb1[tid]  = cb1[tid];
    s_xb1[tid]  = xb1[tid];
    s_xw2v[tid] = xw2[tid];
    s_awv[tid]  = aw[tid];
  } else if (tid < FF + NC){
    s_cb2[tid-FF] = cb2[tid-FF];
  }
  __syncthreads();

  const float abv = ab[0];
  const float xi0 = x[(size_t)bi*3+0], xi1 = x[(size_t)bi*3+1], xi2 = x[(size_t)bi*3+2];

  // ---- geometry (per-wave, lanes<32 write) ----
  {
    const int jl = l & 31;
    const int j  = wave*32 + jl;
    const float xj0 = x[((size_t)(b*NN+j))*3+0];
    const float xj1 = x[((size_t)(b*NN+j))*3+1];
    const float xj2 = x[((size_t)(b*NN+j))*3+2];
    const float dx = xi0-xj0, dy = xi1-xj1, dz = xi2-xj2;
    const float nr = __builtin_amdgcn_sqrtf(dx*dx+dy*dy+dz*dz+EPSF);
    const float inr = rcp_(nr + EPSF);
    if (l < 32){
      s_dx[wave][jl]=dx; s_dy[wave][jl]=dy; s_dz[wave][jl]=dz; s_nr[wave][jl]=nr;
      s_ux[wave][jl]=dx*inr; s_uy[wave][jl]=dy*inr; s_uz[wave][jl]=dz*inr;
    }
  }

  // ---- a1 B-frags: slot(l,e) = a1[j=jt*16+r15][feat=kt*32+g*8+e] ----
  s16x8 a1f[2][2];
  #pragma unroll
  for (int jt=0;jt<2;++jt){
    const int jl = jt*16 + r15;
    const int j  = wave*32 + jl;
    const float nr = s_nr[wave][jl];
    const float* hrow = &hjp_[((size_t)(b*NN+j))*FF];
    #pragma unroll
    for (int kt=0;kt<2;++kt){
      const int fb = kt*32 + g*8;
      const float4 hj0 = *(const float4*)&hrow[fb];
      const float4 hj1 = *(const float4*)&hrow[fb+4];
      const float4 hp0 = *(const float4*)&s_hip[fb];
      const float4 hp1 = *(const float4*)&s_hip[fb+4];
      const float4 e10 = *(const float4*)&s_e1r[fb];
      const float4 e11 = *(const float4*)&s_e1r[fb+4];
      s16x8 fr;
      fr[0] = f2bf(silu_(hp0.x + hj0.x + nr*e10.x));
      fr[1] = f2bf(silu_(hp0.y + hj0.y + nr*e10.y));
      fr[2] = f2bf(silu_(hp0.z + hj0.z + nr*e10.z));
      fr[3] = f2bf(silu_(hp0.w + hj0.w + nr*e10.w));
      fr[4] = f2bf(silu_(hp1.x + hj1.x + nr*e11.x));
      fr[5] = f2bf(silu_(hp1.y + hj1.y + nr*e11.y));
      fr[6] = f2bf(silu_(hp1.z + hj1.z + nr*e11.z));
      fr[7] = f2bf(silu_(hp1.w + hj1.w + nr*e11.w));
      a1f[jt][kt] = fr;
    }
  }

  // ---- E-GEMM: h_e_pre^T = ew2^T x a1^T ----
  f32x4 accE[4][2];
  #pragma unroll
  for (int mt=0;mt<4;++mt){ accE[mt][0]=(f32x4)(0.f); accE[mt][1]=(f32x4)(0.f); }
  #pragma unroll
  for (int kt=0;kt<2;++kt){
    #pragma unroll
    for (int mt=0;mt<4;++mt){
      const s16x8 wf = *(const s16x8*)&s_wE[((mt*2+kt)*64 + l)*8];
      accE[mt][0] = __builtin_amdgcn_mfma_f32_16x16x32_bf16(wf, a1f[0][kt], accE[mt][0], 0,0,0);
      accE[mt][1] = __builtin_amdgcn_mfma_f32_16x16x32_bf16(wf, a1f[1][kt], accE[mt][1], 0,0,0);
    }
  }

  // ---- bias+silu, att gate, hagg, write he^T to scratch ----
  float he[4][2][4];
  float att0p = 0.f, att1p = 0.f;
  #pragma unroll
  for (int mt=0;mt<4;++mt){
    #pragma unroll
    for (int r=0;r<4;++r){
      const int n = mt*16 + g*4 + r;
      const float ebn = s_eb2[n], awn = s_awv[n];
      const float v0 = silu_(accE[mt][0][r] + ebn);
      const float v1 = silu_(accE[mt][1][r] + ebn);
      he[mt][0][r] = v0; he[mt][1][r] = v1;
      att0p += v0*awn; att1p += v1*awn;
    }
  }
  att0p += __shfl_xor(att0p,16,64); att0p += __shfl_xor(att0p,32,64);
  att1p += __shfl_xor(att1p,16,64); att1p += __shfl_xor(att1p,32,64);
  const float att0 = sigmoid_(att0p + abv);
  const float att1 = sigmoid_(att1p + abv);

  char* myT = (char*)&s_sT[wave][0];
  #pragma unroll
  for (int mt=0;mt<4;++mt){
    float hg0[4], hg1[4];
    #pragma unroll
    for (int r=0;r<4;++r){ hg0[r] = he[mt][0][r]*att0; hg1[r] = he[mt][1][r]*att1; }
    #pragma unroll
    for (int r=0;r<4;++r){
      float hp = hg0[r] + hg1[r];
      hp += __shfl_xor(hp,1,64); hp += __shfl_xor(hp,2,64);
      hp += __shfl_xor(hp,4,64); hp += __shfl_xor(hp,8,64);
      if (r15 == 0) s_rh[wave*FF + mt*16 + g*4 + r] = hp;
    }
    #pragma unroll
    for (int jt=0;jt<2;++jt){
      const float* hg = jt ? hg1 : hg0;
      unsigned long long pk =
          (unsigned long long)(unsigned short)f2bf(hg[0])
        | ((unsigned long long)(unsigned short)f2bf(hg[1])<<16)
        | ((unsigned long long)(unsigned short)f2bf(hg[2])<<32)
        | ((unsigned long long)(unsigned short)f2bf(hg[3])<<48);
      const int jl = jt*16 + r15;
      int bo = jl*128 + (mt*16 + g*4)*2;
      bo ^= (jl&7)<<4;
      *(unsigned long long*)(myT + bo) = pk;
    }
  }

  // ---- read he^T B-frags ----
  s16x8 hef[2][2];
  #pragma unroll
  for (int jt=0;jt<2;++jt){
    #pragma unroll
    for (int kt=0;kt<2;++kt){
      const int jl = jt*16 + r15;
      int bo = jl*128 + (kt*32 + g*8)*2;
      bo ^= (jl&7)<<4;
      hef[jt][kt] = *(const s16x8*)(myT + bo);
    }
  }

  // ---- cw1-GEMM and xw1-GEMM ----
  f32x4 accC[4][2], accX[4][2];
  #pragma unroll
  for (int mt=0;mt<4;++mt){ accC[mt][0]=(f32x4)(0.f); accC[mt][1]=(f32x4)(0.f);
                            accX[mt][0]=(f32x4)(0.f); accX[mt][1]=(f32x4)(0.f); }
  #pragma unroll
  for (int kt=0;kt<2;++kt){
    #pragma unroll
    for (int mt=0;mt<4;++mt){
      const s16x8 wfc = *(const s16x8*)&s_wC[((mt*2+kt)*64 + l)*8];
      accC[mt][0] = __builtin_amdgcn_mfma_f32_16x16x32_bf16(wfc, hef[0][kt], accC[mt][0], 0,0,0);
      accC[mt][1] = __builtin_amdgcn_mfma_f32_16x16x32_bf16(wfc, hef[1][kt], accC[mt][1], 0,0,0);
      const s16x8 wfx = *(const s16x8*)&s_wX[((mt*2+kt)*64 + l)*8];
      accX[mt][0] = __builtin_amdgcn_mfma_f32_16x16x32_bf16(wfx, hef[0][kt], accX[mt][0], 0,0,0);
      accX[mt][1] = __builtin_amdgcn_mfma_f32_16x16x32_bf16(wfx, hef[1][kt], accX[mt][1], 0,0,0);
    }
  }

  // ---- trans + x-update (consumes accX) ----
  {
    float tp0 = 0.f, tp1 = 0.f;
    #pragma unroll
    for (int mt=0;mt<4;++mt){
      #pragma unroll
      for (int r=0;r<4;++r){
        const int n = mt*16 + g*4 + r;
        const float xb = s_xb1[n], xv = s_xw2v[n];
        tp0 += silu_(accX[mt][0][r] + xb)*xv;
        tp1 += silu_(accX[mt][1][r] + xb)*xv;
      }
    }
    tp0 += __shfl_xor(tp0,16,64); tp0 += __shfl_xor(tp0,32,64);
    tp1 += __shfl_xor(tp1,16,64); tp1 += __shfl_xor(tp1,32,64);
    if (g == 0){
      float xa0 = s_dx[wave][r15]*tp0 + s_dx[wave][16+r15]*tp1;
      float xa1 = s_dy[wave][r15]*tp0 + s_dy[wave][16+r15]*tp1;
      float xa2 = s_dz[wave][r15]*tp0 + s_dz[wave][16+r15]*tp1;
      #pragma unroll
      for (int m=1;m<16;m<<=1){
        xa0 += __shfl_xor(xa0,m,64); xa1 += __shfl_xor(xa1,m,64); xa2 += __shfl_xor(xa2,m,64);
      }
      if (l == 0){ s_rx[wave*3+0]=xa0; s_rx[wave*3+1]=xa1; s_rx[wave*3+2]=xa2; }
    }
  }

  // ---- c1 = silu(accC + cb1) -> write c1^T to scratch (overwrites he^T) ----
  #pragma unroll
  for (int mt=0;mt<4;++mt){
    #pragma unroll
    for (int jt=0;jt<2;++jt){
      float c0 = silu_(accC[mt][jt][0] + s_cb1[mt*16+g*4+0]);
      float c1v= silu_(accC[mt][jt][1] + s_cb1[mt*16+g*4+1]);
      float c2 = silu_(accC[mt][jt][2] + s_cb1[mt*16+g*4+2]);
      float c3 = silu_(accC[mt][jt][3] + s_cb1[mt*16+g*4+3]);
      unsigned long long pk =
          (unsigned long long)(unsigned short)f2bf(c0)
        | ((unsigned long long)(unsigned short)f2bf(c1v)<<16)
        | ((unsigned long long)(unsigned short)f2bf(c2)<<32)
        | ((unsigned long long)(unsigned short)f2bf(c3)<<48);
      const int jl = jt*16 + r15;
      int bo = jl*128 + (mt*16 + g*4)*2;
      bo ^= (jl&7)<<4;
      *(unsigned long long*)(myT + bo) = pk;
    }
  }

  // ---- cw2-GEMM: coeff^T = cw2^T x c1^T ----
  s16x8 c1f[2][2];
  #pragma unroll
  for (int jt=0;jt<2;++jt){
    #pragma unroll
    for (int kt=0;kt<2;++kt){
      const int jl = jt*16 + r15;
      int bo = jl*128 + (kt*32 + g*8)*2;
      bo ^= (jl&7)<<4;
      c1f[jt][kt] = *(const s16x8*)(myT + bo);
    }
  }
  f32x4 accW[2][2];
  accW[0][0]=(f32x4)(0.f); accW[0][1]=(f32x4)(0.f);
  accW[1][0]=(f32x4)(0.f); accW[1][1]=(f32x4)(0.f);
  #pragma unroll
  for (int kt=0;kt<2;++kt){
    #pragma unroll
    for (int mt=0;mt<2;++mt){
      const s16x8 wf = *(const s16x8*)&s_w2[((mt*2+kt)*64 + l)*8];
      accW[mt][0] = __builtin_amdgcn_mfma_f32_16x16x32_bf16(wf, c1f[0][kt], accW[mt][0], 0,0,0);
      accW[mt][1] = __builtin_amdgcn_mfma_f32_16x16x32_bf16(wf, c1f[1][kt], accW[mt][1], 0,0,0);
    }
  }

  // ---- comb accumulation ----
  {
    const float u0x=s_ux[wave][r15],    u0y=s_uy[wave][r15],    u0z=s_uz[wave][r15];
    const float u1x=s_ux[wave][16+r15], u1y=s_uy[wave][16+r15], u1z=s_uz[wave][16+r15];
    #pragma unroll
    for (int mt=0;mt<2;++mt){
      #pragma unroll
      for (int r=0;r<4;++r){
        const int c = mt*16 + g*4 + r;
        const float cf0 = accW[mt][0][r] + s_cb2[c];
        const float cf1 = accW[mt][1][r] + s_cb2[c];
        float px = u0x*cf0 + u1x*cf1;
        float py = u0y*cf0 + u1y*cf1;
        float pz = u0z*cf0 + u1z*cf1;
        #pragma unroll
        for (int m=1;m<16;m<<=1){
          px += __shfl_xor(px,m,64); py += __shfl_xor(py,m,64); pz += __shfl_xor(pz,m,64);
        }
        if (r15 == 0){
          s_rc[(wave*NC + c)*3+0]=px; s_rc[(wave*NC + c)*3+1]=py; s_rc[(wave*NC + c)*3+2]=pz;
        }
      }
    }
  }

  __syncthreads();

  // ---- Phase 2: node-level MLPs on wave 0 ----
  float haggT = 0.f, hval = 0.f;
  if (wave == 0){
    #pragma unroll
    for (int w=0; w<8; ++w) haggT += s_rh[w*FF + l];
    hval = h[(size_t)bi*FF + l];
    if (l < NC){
      float c0=0.f, c1=0.f, c2=0.f;
      #pragma unroll
      for (int w=0; w<8; ++w){
        c0 += s_rc[(w*NC + l)*3+0];
        c1 += s_rc[(w*NC + l)*3+1];
        c2 += s_rc[(w*NC + l)*3+2];
      }
      s_cn[l] = c0*c0 + c1*c1 + c2*c2;
    }
  }
  __syncthreads();
  if (wave == 0){
    float p1 = pb1[l];
    #pragma unroll 8
    for (int c=0;c<NC;++c) p1 += s_cn[c]*pw1[c*FF + l];
    s_t1[l] = silu_(p1);
  }
  __syncthreads();
  if (wave == 0){
    float p2 = pb2[l];
    #pragma unroll 8
    for (int k=0;k<FF;++k) p2 += s_t1[k]*pw2[k*FF + l];
    s_ni[l] = hval;
    s_ni[FF + l] = haggT;
    s_ni[2*FF + l] = p2;
  }
  __syncthreads();
  if (wave == 0){
    float n1 = nb1[l];
    #pragma unroll 8
    for (int k=0;k<3*FF;++k) n1 += s_ni[k]*nw1[k*FF + l];
    s_t1[l] = silu_(n1);
  }
  __syncthreads();
  if (wave == 0){
    float n2 = nb2[l];
    #pragma unroll 8
    for (int k=0;k<FF;++k) n2 += s_t1[k]*nw2[k*FF + l];
    out_h[(size_t)bi*FF + l] = hval + n2;
    if (l < 3){
      float xs = 0.f;
      #pragma unroll
      for (int w=0; w<8; ++w) xs += s_rx[w*3 + l];
      out_x[(size_t)bi*3 + l] = x[(size_t)bi*3 + l] + xs*(1.0f/256.0f);
    }
  }
}

extern "C" void kernel_launch(void* const* d_in, const int* in_sizes, int n_in,
                              void* d_out, int out_size, void* d_ws, size_t ws_size,
                              hipStream_t stream) {
  const float* h   = (const float*)d_in[0];
  const float* x   = (const float*)d_in[1];
  const float* ew1 = (const float*)d_in[2];
  const float* eb1 = (const float*)d_in[3];
  const float* ew2 = (const float*)d_in[4];
  const float* eb2 = (const float*)d_in[5];
  const float* aw  = (const float*)d_in[6];
  const float* ab  = (const float*)d_in[7];
  const float* cw1 = (const float*)d_in[8];
  const float* cb1 = (const float*)d_in[9];
  const float* cw2 = (const float*)d_in[10];
  const float* cb2 = (const float*)d_in[11];
  const float* pw1 = (const float*)d_in[12];
  const float* pb1 = (const float*)d_in[13];
  const float* pw2 = (const float*)d_in[14];
  const float* pb2 = (const float*)d_in[15];
  const float* nw1 = (const float*)d_in[16];
  const float* nb1 = (const float*)d_in[17];
  const float* nw2 = (const float*)d_in[18];
  const float* nb2 = (const float*)d_in[19];
  const float* xw1 = (const float*)d_in[20];
  const float* xb1 = (const float*)d_in[21];
  const float* xw2 = (const float*)d_in[22];

  float* hip_ = (float*)d_ws;
  float* hjp_ = hip_ + (size_t)NB*NN*FF;
  float* out_h = (float*)d_out;
  float* out_x = out_h + (size_t)NB*NN*FF;

  sake_proj<<<NB*NN, 64, 0, stream>>>(h, ew1, eb1, hip_, hjp_);
  sake_main<<<NB*NN, 512, 0, stream>>>(h, x, ew1, ew2, eb2, aw, ab, cw1, cb1, cw2, cb2,
                                       pw1, pb1, pw2, pb2, nw1, nb1, nw2, nb2,
                                       xw1, xb1, xw2, hip_, hjp_, out_h, out_x);
}